// Round 1
// baseline (252.535 us; speedup 1.0000x reference)
//
#include <hip/hip_runtime.h>

#define EPSF 1e-8f
#define CCH 128
#define HWSZ 65536
#define NPIX 262144
#define KTOP 13107
#define LN2F 0.6931471805599453f

// ws layout (32-bit words)
#define WS_SUM    0      // [512] f32: sumP[128], sumsqP[128], sumT[128], sumsqT[128]
#define WS_CST    512    // [512] f32: float4 per slot (bm_p, bi_p, bm_t, bi_t), slot=(c&31)*4+(c>>5)
#define WS_WGT    1024   // [9] f32 softmax weights
#define WS_MINKEY 1040
#define WS_MAXKEY 1041
#define WS_BSTAR  1042
#define WS_CNTAB  1043
#define WS_LO2    1044
#define WS_W2     1045
#define WS_K2     1046
#define WS_SUMAB  1048
#define WS_H1     1056   // [4096] u32
#define WS_H2C    5152   // [4096] u32
#define WS_H2S    9248   // [4096] f32
#define WS_TOTAL  13344

__device__ __forceinline__ unsigned fkey(float f){
  unsigned u = __float_as_uint(f);
  return (u & 0x80000000u) ? ~u : (u | 0x80000000u);
}
__device__ __forceinline__ float funkey(unsigned k){
  unsigned u = (k & 0x80000000u) ? (k & 0x7fffffffu) : ~k;
  return __uint_as_float(u);
}

__global__ __launch_bounds__(256) void initWs(unsigned* __restrict__ wsu){
  int idx = blockIdx.x*256 + threadIdx.x;
  if (idx < WS_TOTAL) wsu[idx] = (idx == WS_MINKEY) ? 0xFFFFFFFFu : 0u;
}

// per-channel sums over (B,H,W) for both tensors
__global__ __launch_bounds__(512) void bnSumKernel(const float* __restrict__ rec,
                                                   const float* __restrict__ tgt,
                                                   float* __restrict__ wsf){
  int blk = blockIdx.x;            // 0..1023: tensor(2) x b(4) x c(128)
  int tensor = blk >> 9;
  int rem = blk & 511;
  int c = rem & 127;
  int b = rem >> 7;
  const float* src = (tensor==0 ? rec : tgt) + ((size_t)(b*CCH + c))*HWSZ;
  const float4* src4 = (const float4*)src;
  float s=0.f, q=0.f;
  for (int j=threadIdx.x; j<HWSZ/4; j+=512){
    float4 v = src4[j];
    s += v.x+v.y+v.z+v.w;
    q += v.x*v.x + v.y*v.y + v.z*v.z + v.w*v.w;
  }
  for (int off=1; off<64; off<<=1){ s += __shfl_xor(s,off); q += __shfl_xor(q,off); }
  __shared__ float ls[8], lq[8];
  int wid = threadIdx.x >> 6;
  if ((threadIdx.x & 63)==0){ ls[wid]=s; lq[wid]=q; }
  __syncthreads();
  if (threadIdx.x==0){
    float S=0,Q=0;
    for (int i=0;i<8;i++){ S+=ls[i]; Q+=lq[i]; }
    atomicAdd(&wsf[tensor*256 + c], S);
    atomicAdd(&wsf[tensor*256 + 128 + c], Q);
  }
}

// bn mean/inv-std per channel (both tensors) + softmax weights
__global__ __launch_bounds__(256) void finalizeKernel(const float* __restrict__ lw,
                                                      float* __restrict__ wsf){
  int tid = threadIdx.x;
  {
    int tensor = tid >> 7;
    int c = tid & 127;
    float S = wsf[tensor*256 + c];
    float Q = wsf[tensor*256 + 128 + c];
    const float N = 262144.f;
    float mean = S / N;
    float var = fmaxf((Q - S*S/N) / (N - 1.f), 0.f);
    float inv = 1.f/(sqrtf(var)+EPSF);
    int slot = (c & 31)*4 + (c >> 5);
    wsf[WS_CST + slot*4 + tensor*2 + 0] = mean;
    wsf[WS_CST + slot*4 + tensor*2 + 1] = inv;
  }
  if (tid==0){
    float m = -1e30f;
    for (int i=0;i<9;i++) m = fmaxf(m, lw[i]);
    float e[9], sum=0.f;
    for (int i=0;i<9;i++){ e[i]=expf(lw[i]-m); sum+=e[i]; }
    for (int i=0;i<9;i++) wsf[WS_WGT+i] = e[i]/sum;
  }
}

// main per-pixel kernel: 4 lanes/pixel, 32 channels each, everything in VGPRs
__global__ __launch_bounds__(256) void mainKernel(const float* __restrict__ rec,
                                                  const float* __restrict__ tgt,
                                                  const float* __restrict__ wsf,
                                                  unsigned* __restrict__ wsu,
                                                  float* __restrict__ errMap){
  __shared__ float4 cst[128];
  __shared__ float wgt[16];
  __shared__ float rmn[4], rmx[4];
  int tid = threadIdx.x;
  if (tid < 128) cst[tid] = ((const float4*)(wsf + WS_CST))[tid];
  if (tid < 9)  wgt[tid] = wsf[WS_WGT + tid];
  __syncthreads();

  int P = blockIdx.x*64 + (tid>>2);
  int q = tid & 3;
  int b = P >> 16;
  int hw = P & (HWSZ-1);
  const float* pB = rec + ((size_t)(b*CCH + q*32))*HWSZ + hw;
  const float* tB = tgt + ((size_t)(b*CCH + q*32))*HWSZ + hw;

  float p[32], t[32];
  float psum=0,psumsq=0,tsum=0,tsumsq=0,ptsum=0;
  float pmin=3.4e38f, pmax=-3.4e38f, tmin=3.4e38f, tmax=-3.4e38f;
  float bS1=0,bS11=0,bS2=0,bS22=0,bS12=0,bMp=3.4e38f,bMt=3.4e38f;

  #pragma unroll
  for (int i=0;i<32;i++){
    float pv = pB[(size_t)i*HWSZ];
    float tv = tB[(size_t)i*HWSZ];
    p[i]=pv; t[i]=tv;
    psum+=pv; psumsq+=pv*pv;
    tsum+=tv; tsumsq+=tv*tv;
    ptsum+=pv*tv;
    pmin=fminf(pmin,pv); pmax=fmaxf(pmax,pv);
    tmin=fminf(tmin,tv); tmax=fmaxf(tmax,tv);
    float4 c4 = cst[i*4+q];
    float bp=(pv-c4.x)*c4.y, bt=(tv-c4.z)*c4.w;
    bS1+=bp; bS11+=bp*bp; bS2+=bt; bS22+=bt*bt; bS12+=bp*bt;
    bMp=fminf(bMp,bp); bMt=fminf(bMt,bt);
  }

  #define RADD(v) v += __shfl_xor(v,1); v += __shfl_xor(v,2)
  #define RMIN(v) v = fminf(v,__shfl_xor(v,1)); v = fminf(v,__shfl_xor(v,2))
  #define RMAX(v) v = fmaxf(v,__shfl_xor(v,1)); v = fmaxf(v,__shfl_xor(v,2))
  RADD(psum); RADD(psumsq); RADD(tsum); RADD(tsumsq); RADD(ptsum);
  RMIN(pmin); RMIN(tmin); RMAX(pmax); RMAX(tmax);
  RADD(bS1); RADD(bS11); RADD(bS2); RADD(bS22); RADD(bS12);
  RMIN(bMp); RMIN(bMt);

  const float Ci = 1.0f/128.0f;
  float smm_p = 1.f/(pmax-pmin+EPSF);
  float smm_t = 1.f/(tmax-tmin+EPSF);
  float mean_p = psum*Ci, mean_t = tsum*Ci;
  float var_p = fmaxf((psumsq - psum*psum*Ci)*(1.f/127.f), 0.f);
  float var_t = fmaxf((tsumsq - tsum*tsum*Ci)*(1.f/127.f), 0.f);
  float zi_p = 1.f/(sqrtf(var_p)+EPSF);
  float zi_t = 1.f/(sqrtf(var_t)+EPSF);

  auto metrics = [](float S1,float S11,float S2,float S22,float S12,float& sam,float& pear){
    float npn = fmaxf(sqrtf(fmaxf(S11,0.f)), EPSF);
    float ntn = fmaxf(sqrtf(fmaxf(S22,0.f)), EPSF);
    sam = 1.f - S12/(npn*ntn);
    const float ci = 1.0f/128.0f;
    float cov = S12 - S1*S2*ci;
    float vp = fmaxf(S11 - S1*S1*ci, 0.f);
    float vt = fmaxf(S22 - S2*S2*ci, 0.f);
    pear = 1.f - cov/(sqrtf(vp+EPSF)*sqrtf(vt+EPSF));
  };
  auto affine = [&](float ap,float sp,float at,float st,float& sam,float& pear){
    float S1 = (psum - 128.f*ap)*sp;
    float S11 = (psumsq - 2.f*ap*psum + 128.f*ap*ap)*sp*sp;
    float S2 = (tsum - 128.f*at)*st;
    float S22 = (tsumsq - 2.f*at*tsum + 128.f*at*at)*st*st;
    float S12 = (ptsum - at*psum - ap*tsum + 128.f*ap*at)*sp*st;
    metrics(S1,S11,S2,S22,S12,sam,pear);
  };

  float sam_mm,pear_mm,sam_z,pear_z,sam_bn,pear_bn;
  affine(pmin,smm_p,tmin,smm_t,sam_mm,pear_mm);
  affine(mean_p,zi_p,mean_t,zi_t,sam_z,pear_z);
  metrics(bS1,bS11,bS2,bS22,bS12,sam_bn,pear_bn);

  // SID: shared for minmax/z (EPS-placement difference ~1e-9), separate for bn
  float fp = smm_p / ((psum - 128.f*pmin)*smm_p + EPSF);
  float ft = smm_t / ((tsum - 128.f*tmin)*smm_t + EPSF);
  float fbp = 1.f/((bS1 - 128.f*bMp) + EPSF);
  float fbt = 1.f/((bS2 - 128.f*bMt) + EPSF);
  float sid_mm = 0.f, sid_bn = 0.f;
  #pragma unroll
  for (int i=0;i<32;i++){
    float pp = fmaxf((p[i]-pmin)*fp, EPSF);
    float tp = fmaxf((t[i]-tmin)*ft, EPSF);
    sid_mm += (pp-tp)*(__log2f(pp)-__log2f(tp));
    float4 c4 = cst[i*4+q];
    float bp = (p[i]-c4.x)*c4.y;
    float bt = (t[i]-c4.z)*c4.w;
    float qp = fmaxf((bp-bMp)*fbp, EPSF);
    float qt = fmaxf((bt-bMt)*fbt, EPSF);
    sid_bn += (qp-qt)*(__log2f(qp)-__log2f(qt));
  }
  RADD(sid_mm); RADD(sid_bn);
  sid_mm *= LN2F; sid_bn *= LN2F;

  float err = wgt[0]*sam_mm + wgt[1]*pear_mm + wgt[2]*sid_mm
            + wgt[3]*sam_z  + wgt[4]*pear_z  + wgt[5]*sid_mm
            + wgt[6]*sam_bn + wgt[7]*pear_bn + wgt[8]*sid_bn;
  if (q==0) errMap[P] = err;

  // block min/max of err -> global ordered-key atomics
  float emin = err, emax = err;
  #pragma unroll
  for (int off=1; off<64; off<<=1){
    emin = fminf(emin, __shfl_xor(emin,off));
    emax = fmaxf(emax, __shfl_xor(emax,off));
  }
  int wv = tid>>6;
  if ((tid&63)==0){ rmn[wv]=emin; rmx[wv]=emax; }
  __syncthreads();
  if (tid==0){
    emin = fminf(fminf(rmn[0],rmn[1]),fminf(rmn[2],rmn[3]));
    emax = fmaxf(fmaxf(rmx[0],rmx[1]),fmaxf(rmx[2],rmx[3]));
    atomicMin(&wsu[WS_MINKEY], fkey(emin));
    atomicMax(&wsu[WS_MAXKEY], fkey(emax));
  }
  #undef RADD
  #undef RMIN
  #undef RMAX
}

__global__ __launch_bounds__(256) void hist1Kernel(const float* __restrict__ err,
                                                   unsigned* __restrict__ wsu){
  __shared__ unsigned h[4096];
  int tid = threadIdx.x;
  for (int i=tid;i<4096;i+=256) h[i]=0u;
  __syncthreads();
  float lo = funkey(wsu[WS_MINKEY]);
  float hi = funkey(wsu[WS_MAXKEY]);
  float invw = 4096.f / fmaxf(hi-lo, 1e-30f);
  int base = blockIdx.x*2048 + tid;
  for (int j=0;j<8;j++){
    float v = err[base + j*256];
    int idx = (int)fminf(fmaxf((v-lo)*invw, 0.f), 4095.f);
    atomicAdd(&h[idx], 1u);
  }
  __syncthreads();
  for (int i=tid;i<4096;i+=256){ unsigned c=h[i]; if (c) atomicAdd(&wsu[WS_H1+i], c); }
}

__global__ __launch_bounds__(256) void scan1Kernel(float* __restrict__ wsf,
                                                   unsigned* __restrict__ wsu){
  __shared__ unsigned counts[4096];
  __shared__ unsigned s[256];
  int tid = threadIdx.x;
  for (int i=tid;i<4096;i+=256) counts[i]=wsu[WS_H1+i];
  __syncthreads();
  unsigned part=0;
  for (int j=0;j<16;j++) part += counts[tid*16+j];
  s[tid]=part; __syncthreads();
  for (int off=1; off<256; off<<=1){
    unsigned v = (tid+off<256)? s[tid+off] : 0u;
    __syncthreads();
    s[tid] += v;
    __syncthreads();
  }
  float lo = funkey(wsu[WS_MINKEY]);
  float hi = funkey(wsu[WS_MAXKEY]);
  float w1 = fmaxf(hi-lo, 1e-30f) * (1.f/4096.f);
  unsigned cum = (tid<255)? s[tid+1] : 0u;
  for (int j=15;j>=0;j--){
    int bin = tid*16+j;
    unsigned cn = cum + counts[bin];
    if (cum < (unsigned)KTOP && cn >= (unsigned)KTOP){
      wsu[WS_BSTAR] = (unsigned)bin;
      wsu[WS_CNTAB] = cum;
      wsu[WS_K2]    = (unsigned)KTOP - cum;
      wsf[WS_LO2]   = lo + (float)bin*w1;
      wsf[WS_W2]    = w1*(1.f/4096.f);
    }
    cum = cn;
  }
}

__global__ __launch_bounds__(256) void hist2Kernel(const float* __restrict__ err,
                                                   float* __restrict__ wsf,
                                                   unsigned* __restrict__ wsu){
  __shared__ unsigned h2[4096];
  __shared__ float s2[4096];
  __shared__ float ls[4];
  int tid = threadIdx.x;
  for (int i=tid;i<4096;i+=256){ h2[i]=0u; s2[i]=0.f; }
  __syncthreads();
  float lo = funkey(wsu[WS_MINKEY]);
  float hi = funkey(wsu[WS_MAXKEY]);
  float invw = 4096.f / fmaxf(hi-lo, 1e-30f);
  int bstar = (int)wsu[WS_BSTAR];
  float lo2 = wsf[WS_LO2];
  float w2  = wsf[WS_W2];
  float invw2 = 1.f / w2;
  float mySum = 0.f;
  int base = blockIdx.x*2048 + tid;
  for (int j=0;j<8;j++){
    float v = err[base + j*256];
    int idx = (int)fminf(fmaxf((v-lo)*invw, 0.f), 4095.f);
    if (idx > bstar){
      mySum += v;
    } else if (idx == bstar){
      int i2 = (int)fminf(fmaxf((v-lo2)*invw2, 0.f), 4095.f);
      atomicAdd(&h2[i2], 1u);
      atomicAdd(&s2[i2], v);
    }
  }
  for (int off=1; off<64; off<<=1) mySum += __shfl_xor(mySum, off);
  if ((tid&63)==0) ls[tid>>6] = mySum;
  __syncthreads();
  if (tid==0) atomicAdd(&wsf[WS_SUMAB], ls[0]+ls[1]+ls[2]+ls[3]);
  for (int i=tid;i<4096;i+=256){
    unsigned c = h2[i]; if (c) atomicAdd(&wsu[WS_H2C+i], c);
    float sv = s2[i];   if (sv != 0.f) atomicAdd(&wsf[WS_H2S+i], sv);
  }
}

__global__ __launch_bounds__(256) void scan2Kernel(float* __restrict__ wsf,
                                                   unsigned* __restrict__ wsu,
                                                   float* __restrict__ out){
  __shared__ unsigned cnt[4096];
  __shared__ float sm[4096];
  __shared__ unsigned sC[256];
  __shared__ float sS[256];
  int tid = threadIdx.x;
  for (int i=tid;i<4096;i+=256){ cnt[i]=wsu[WS_H2C+i]; sm[i]=wsf[WS_H2S+i]; }
  __syncthreads();
  unsigned pc=0; float ps=0.f;
  for (int j=0;j<16;j++){ pc+=cnt[tid*16+j]; ps+=sm[tid*16+j]; }
  sC[tid]=pc; sS[tid]=ps; __syncthreads();
  for (int off=1; off<256; off<<=1){
    unsigned vc = (tid+off<256)? sC[tid+off] : 0u;
    float vs    = (tid+off<256)? sS[tid+off] : 0.f;
    __syncthreads();
    sC[tid] += vc; sS[tid] += vs;
    __syncthreads();
  }
  unsigned k2 = wsu[WS_K2];
  float lo2 = wsf[WS_LO2], w2 = wsf[WS_W2];
  unsigned cum = (tid<255)? sC[tid+1] : 0u;
  float cums   = (tid<255)? sS[tid+1] : 0.f;
  for (int j=15;j>=0;j--){
    int bin = tid*16+j;
    unsigned cn = cum + cnt[bin];
    float sn = cums + sm[bin];
    if (cum < k2 && cn >= k2){
      float val = lo2 + ((float)bin + 0.5f)*w2;
      float total = wsf[WS_SUMAB] + cums + (float)(k2 - cum)*val;
      out[0] = total / (float)KTOP;
    }
    cum = cn; cums = sn;
  }
}

extern "C" void kernel_launch(void* const* d_in, const int* in_sizes, int n_in,
                              void* d_out, int out_size, void* d_ws, size_t ws_size,
                              hipStream_t stream){
  const float* rec = (const float*)d_in[0];
  const float* tgt = (const float*)d_in[1];
  const float* lw  = (const float*)d_in[2];
  float* out = (float*)d_out;
  float* wsf = (float*)d_ws;
  unsigned* wsu = (unsigned*)d_ws;

  hipLaunchKernelGGL(initWs, dim3((WS_TOTAL+255)/256), dim3(256), 0, stream, wsu);
  hipLaunchKernelGGL(bnSumKernel, dim3(1024), dim3(512), 0, stream, rec, tgt, wsf);
  hipLaunchKernelGGL(finalizeKernel, dim3(1), dim3(256), 0, stream, lw, wsf);
  hipLaunchKernelGGL(mainKernel, dim3(NPIX/64), dim3(256), 0, stream, rec, tgt, wsf, wsu, out+1);
  hipLaunchKernelGGL(hist1Kernel, dim3(128), dim3(256), 0, stream, out+1, wsu);
  hipLaunchKernelGGL(scan1Kernel, dim3(1), dim3(256), 0, stream, wsf, wsu);
  hipLaunchKernelGGL(hist2Kernel, dim3(128), dim3(256), 0, stream, out+1, wsf, wsu);
  hipLaunchKernelGGL(scan2Kernel, dim3(1), dim3(256), 0, stream, wsf, wsu, out);
}

// Round 2
// 243.808 us; speedup vs baseline: 1.0358x; 1.0358x over previous
//
#include <hip/hip_runtime.h>

#define EPSF 1e-8f
#define CCH 128
#define HWSZ 65536
#define NPIX 262144
#define KTOP 13107
#define LN2F 0.6931471805599453f

// ws layout (32-bit words)
#define WS_SUM    0      // [512] f32: sumP[128], sumsqP[128], sumT[128], sumsqT[128]
#define WS_CST    512    // [512] f32: float4 per slot (bm_p, bi_p, bm_t, bi_t), slot=(c&31)*4+(c>>5)
#define WS_WGT    1024   // [9] f32 softmax weights
#define WS_MINKEY 1040
#define WS_MAXKEY 1041
#define WS_BSTAR  1042
#define WS_CNTAB  1043
#define WS_LO2    1044
#define WS_W2     1045
#define WS_K2     1046
#define WS_SUMAB  1048
#define WS_H1     1056   // [4096] u32
#define WS_H2C    5152   // [4096] u32
#define WS_H2S    9248   // [4096] f32
#define WS_TOTAL  13344

__device__ __forceinline__ unsigned fkey(float f){
  unsigned u = __float_as_uint(f);
  return (u & 0x80000000u) ? ~u : (u | 0x80000000u);
}
__device__ __forceinline__ float funkey(unsigned k){
  unsigned u = (k & 0x80000000u) ? (k & 0x7fffffffu) : ~k;
  return __uint_as_float(u);
}

__global__ __launch_bounds__(256) void initWs(unsigned* __restrict__ wsu){
  int idx = blockIdx.x*256 + threadIdx.x;
  if (idx < WS_TOTAL) wsu[idx] = (idx == WS_MINKEY) ? 0xFFFFFFFFu : 0u;
}

// per-channel sums over (B,H,W) for both tensors
__global__ __launch_bounds__(512) void bnSumKernel(const float* __restrict__ rec,
                                                   const float* __restrict__ tgt,
                                                   float* __restrict__ wsf){
  int blk = blockIdx.x;            // 0..1023: tensor(2) x b(4) x c(128)
  int tensor = blk >> 9;
  int rem = blk & 511;
  int c = rem & 127;
  int b = rem >> 7;
  const float* src = (tensor==0 ? rec : tgt) + ((size_t)(b*CCH + c))*HWSZ;
  const float4* src4 = (const float4*)src;
  float s=0.f, q=0.f;
  for (int j=threadIdx.x; j<HWSZ/4; j+=512){
    float4 v = src4[j];
    s += v.x+v.y+v.z+v.w;
    q += v.x*v.x + v.y*v.y + v.z*v.z + v.w*v.w;
  }
  for (int off=1; off<64; off<<=1){ s += __shfl_xor(s,off); q += __shfl_xor(q,off); }
  __shared__ float ls[8], lq[8];
  int wid = threadIdx.x >> 6;
  if ((threadIdx.x & 63)==0){ ls[wid]=s; lq[wid]=q; }
  __syncthreads();
  if (threadIdx.x==0){
    float S=0,Q=0;
    for (int i=0;i<8;i++){ S+=ls[i]; Q+=lq[i]; }
    atomicAdd(&wsf[tensor*256 + c], S);
    atomicAdd(&wsf[tensor*256 + 128 + c], Q);
  }
}

// bn mean/inv-std per channel (both tensors) + softmax weights
__global__ __launch_bounds__(256) void finalizeKernel(const float* __restrict__ lw,
                                                      float* __restrict__ wsf){
  int tid = threadIdx.x;
  {
    int tensor = tid >> 7;
    int c = tid & 127;
    float S = wsf[tensor*256 + c];
    float Q = wsf[tensor*256 + 128 + c];
    const float N = 262144.f;
    float mean = S / N;
    float var = fmaxf((Q - S*S/N) / (N - 1.f), 0.f);
    float inv = 1.f/(sqrtf(var)+EPSF);
    int slot = (c & 31)*4 + (c >> 5);
    wsf[WS_CST + slot*4 + tensor*2 + 0] = mean;
    wsf[WS_CST + slot*4 + tensor*2 + 1] = inv;
  }
  if (tid==0){
    float m = -1e30f;
    for (int i=0;i<9;i++) m = fmaxf(m, lw[i]);
    float e[9], sum=0.f;
    for (int i=0;i<9;i++){ e[i]=expf(lw[i]-m); sum+=e[i]; }
    for (int i=0;i<9;i++) wsf[WS_WGT+i] = e[i]/sum;
  }
}

// main per-pixel kernel: wave w owns channels [32w,32w+32), lane l owns pixel l
// -> every global load is 64 lanes x 4B consecutive = 256B coalesced.
__global__ __launch_bounds__(256) void mainKernel(const float* __restrict__ rec,
                                                  const float* __restrict__ tgt,
                                                  const float* __restrict__ wsf,
                                                  unsigned* __restrict__ wsu,
                                                  float* __restrict__ errMap){
  __shared__ float4 cst[128];
  __shared__ float wgt[16];
  __shared__ float red[16][4][64];
  __shared__ float sidred[2][4][64];
  int tid = threadIdx.x;
  if (tid < 128) cst[tid] = ((const float4*)(wsf + WS_CST))[tid];
  if (tid < 9)  wgt[tid] = wsf[WS_WGT + tid];
  __syncthreads();

  int w = tid >> 6;        // wave = channel group
  int l = tid & 63;        // lane = pixel within block
  int P = blockIdx.x*64 + l;
  int b = P >> 16;
  int hw = P & (HWSZ-1);
  const float* pB = rec + ((size_t)(b*CCH + w*32))*HWSZ + hw;
  const float* tB = tgt + ((size_t)(b*CCH + w*32))*HWSZ + hw;

  float p[32], t[32];
  float psum=0,psumsq=0,tsum=0,tsumsq=0,ptsum=0;
  float pmin=3.4e38f, pmax=-3.4e38f, tmin=3.4e38f, tmax=-3.4e38f;
  float bS1=0,bS11=0,bS2=0,bS22=0,bS12=0,bMp=3.4e38f,bMt=3.4e38f;

  #pragma unroll
  for (int i=0;i<32;i++){
    float pv = pB[(size_t)i*HWSZ];
    float tv = tB[(size_t)i*HWSZ];
    p[i]=pv; t[i]=tv;
    psum+=pv; psumsq+=pv*pv;
    tsum+=tv; tsumsq+=tv*tv;
    ptsum+=pv*tv;
    pmin=fminf(pmin,pv); pmax=fmaxf(pmax,pv);
    tmin=fminf(tmin,tv); tmax=fmaxf(tmax,tv);
    float4 c4 = cst[i*4+w];
    float bp=(pv-c4.x)*c4.y, bt=(tv-c4.z)*c4.w;
    bS1+=bp; bS11+=bp*bp; bS2+=bt; bS22+=bt*bt; bS12+=bp*bt;
    bMp=fminf(bMp,bp); bMt=fminf(bMt,bt);
  }

  // cross-wave (channel-group) combine via LDS
  red[0][w][l]=psum;  red[1][w][l]=psumsq; red[2][w][l]=tsum;  red[3][w][l]=tsumsq;
  red[4][w][l]=ptsum; red[5][w][l]=pmin;   red[6][w][l]=pmax;  red[7][w][l]=tmin;
  red[8][w][l]=tmax;  red[9][w][l]=bS1;    red[10][w][l]=bS11; red[11][w][l]=bS2;
  red[12][w][l]=bS22; red[13][w][l]=bS12;  red[14][w][l]=bMp;  red[15][w][l]=bMt;
  __syncthreads();

  #define RSUM(s) (red[s][0][l]+red[s][1][l]+red[s][2][l]+red[s][3][l])
  #define RMN(s)  fminf(fminf(red[s][0][l],red[s][1][l]),fminf(red[s][2][l],red[s][3][l]))
  #define RMX(s)  fmaxf(fmaxf(red[s][0][l],red[s][1][l]),fmaxf(red[s][2][l],red[s][3][l]))
  psum=RSUM(0); psumsq=RSUM(1); tsum=RSUM(2); tsumsq=RSUM(3); ptsum=RSUM(4);
  pmin=RMN(5); pmax=RMX(6); tmin=RMN(7); tmax=RMX(8);
  bS1=RSUM(9); bS11=RSUM(10); bS2=RSUM(11); bS22=RSUM(12); bS12=RSUM(13);
  bMp=RMN(14); bMt=RMN(15);
  #undef RSUM
  #undef RMN
  #undef RMX

  const float Ci = 1.0f/128.0f;
  float smm_p = 1.f/(pmax-pmin+EPSF);
  float smm_t = 1.f/(tmax-tmin+EPSF);
  float mean_p = psum*Ci, mean_t = tsum*Ci;
  float var_p = fmaxf((psumsq - psum*psum*Ci)*(1.f/127.f), 0.f);
  float var_t = fmaxf((tsumsq - tsum*tsum*Ci)*(1.f/127.f), 0.f);
  float zi_p = 1.f/(sqrtf(var_p)+EPSF);
  float zi_t = 1.f/(sqrtf(var_t)+EPSF);

  auto metrics = [](float S1,float S11,float S2,float S22,float S12,float& sam,float& pear){
    float npn = fmaxf(sqrtf(fmaxf(S11,0.f)), EPSF);
    float ntn = fmaxf(sqrtf(fmaxf(S22,0.f)), EPSF);
    sam = 1.f - S12/(npn*ntn);
    const float ci = 1.0f/128.0f;
    float cov = S12 - S1*S2*ci;
    float vp = fmaxf(S11 - S1*S1*ci, 0.f);
    float vt = fmaxf(S22 - S2*S2*ci, 0.f);
    pear = 1.f - cov/(sqrtf(vp+EPSF)*sqrtf(vt+EPSF));
  };
  auto affine = [&](float ap,float sp,float at,float st,float& sam,float& pear){
    float S1 = (psum - 128.f*ap)*sp;
    float S11 = (psumsq - 2.f*ap*psum + 128.f*ap*ap)*sp*sp;
    float S2 = (tsum - 128.f*at)*st;
    float S22 = (tsumsq - 2.f*at*tsum + 128.f*at*at)*st*st;
    float S12 = (ptsum - at*psum - ap*tsum + 128.f*ap*at)*sp*st;
    metrics(S1,S11,S2,S22,S12,sam,pear);
  };

  float sam_mm,pear_mm,sam_z,pear_z,sam_bn,pear_bn;
  affine(pmin,smm_p,tmin,smm_t,sam_mm,pear_mm);
  affine(mean_p,zi_p,mean_t,zi_t,sam_z,pear_z);
  metrics(bS1,bS11,bS2,bS22,bS12,sam_bn,pear_bn);

  // SID: shared for minmax/z (EPS-placement difference ~1e-9), separate for bn
  float fp = smm_p / ((psum - 128.f*pmin)*smm_p + EPSF);
  float ft = smm_t / ((tsum - 128.f*tmin)*smm_t + EPSF);
  float fbp = 1.f/((bS1 - 128.f*bMp) + EPSF);
  float fbt = 1.f/((bS2 - 128.f*bMt) + EPSF);
  float sid_mm = 0.f, sid_bn = 0.f;
  #pragma unroll
  for (int i=0;i<32;i++){
    float pp = fmaxf((p[i]-pmin)*fp, EPSF);
    float tp = fmaxf((t[i]-tmin)*ft, EPSF);
    sid_mm += (pp-tp)*(__log2f(pp)-__log2f(tp));
    float4 c4 = cst[i*4+w];
    float bp = (p[i]-c4.x)*c4.y;
    float bt = (t[i]-c4.z)*c4.w;
    float qp = fmaxf((bp-bMp)*fbp, EPSF);
    float qt = fmaxf((bt-bMt)*fbt, EPSF);
    sid_bn += (qp-qt)*(__log2f(qp)-__log2f(qt));
  }
  sidred[0][w][l]=sid_mm; sidred[1][w][l]=sid_bn;
  __syncthreads();

  if (w==0){
    sid_mm = (sidred[0][0][l]+sidred[0][1][l]+sidred[0][2][l]+sidred[0][3][l])*LN2F;
    sid_bn = (sidred[1][0][l]+sidred[1][1][l]+sidred[1][2][l]+sidred[1][3][l])*LN2F;
    float err = wgt[0]*sam_mm + wgt[1]*pear_mm + wgt[2]*sid_mm
              + wgt[3]*sam_z  + wgt[4]*pear_z  + wgt[5]*sid_mm
              + wgt[6]*sam_bn + wgt[7]*pear_bn + wgt[8]*sid_bn;
    errMap[P] = err;

    float emin = err, emax = err;
    #pragma unroll
    for (int off=1; off<64; off<<=1){
      emin = fminf(emin, __shfl_xor(emin,off));
      emax = fmaxf(emax, __shfl_xor(emax,off));
    }
    if (l==0){
      atomicMin(&wsu[WS_MINKEY], fkey(emin));
      atomicMax(&wsu[WS_MAXKEY], fkey(emax));
    }
  }
}

__global__ __launch_bounds__(256) void hist1Kernel(const float* __restrict__ err,
                                                   unsigned* __restrict__ wsu){
  __shared__ unsigned h[4096];
  int tid = threadIdx.x;
  for (int i=tid;i<4096;i+=256) h[i]=0u;
  __syncthreads();
  float lo = funkey(wsu[WS_MINKEY]);
  float hi = funkey(wsu[WS_MAXKEY]);
  float invw = 4096.f / fmaxf(hi-lo, 1e-30f);
  int base = blockIdx.x*2048 + tid;
  for (int j=0;j<8;j++){
    float v = err[base + j*256];
    int idx = (int)fminf(fmaxf((v-lo)*invw, 0.f), 4095.f);
    atomicAdd(&h[idx], 1u);
  }
  __syncthreads();
  for (int i=tid;i<4096;i+=256){ unsigned c=h[i]; if (c) atomicAdd(&wsu[WS_H1+i], c); }
}

__global__ __launch_bounds__(256) void scan1Kernel(float* __restrict__ wsf,
                                                   unsigned* __restrict__ wsu){
  __shared__ unsigned counts[4096];
  __shared__ unsigned s[256];
  int tid = threadIdx.x;
  for (int i=tid;i<4096;i+=256) counts[i]=wsu[WS_H1+i];
  __syncthreads();
  unsigned part=0;
  for (int j=0;j<16;j++) part += counts[tid*16+j];
  s[tid]=part; __syncthreads();
  for (int off=1; off<256; off<<=1){
    unsigned v = (tid+off<256)? s[tid+off] : 0u;
    __syncthreads();
    s[tid] += v;
    __syncthreads();
  }
  float lo = funkey(wsu[WS_MINKEY]);
  float hi = funkey(wsu[WS_MAXKEY]);
  float w1 = fmaxf(hi-lo, 1e-30f) * (1.f/4096.f);
  unsigned cum = (tid<255)? s[tid+1] : 0u;
  for (int j=15;j>=0;j--){
    int bin = tid*16+j;
    unsigned cn = cum + counts[bin];
    if (cum < (unsigned)KTOP && cn >= (unsigned)KTOP){
      wsu[WS_BSTAR] = (unsigned)bin;
      wsu[WS_CNTAB] = cum;
      wsu[WS_K2]    = (unsigned)KTOP - cum;
      wsf[WS_LO2]   = lo + (float)bin*w1;
      wsf[WS_W2]    = w1*(1.f/4096.f);
    }
    cum = cn;
  }
}

__global__ __launch_bounds__(256) void hist2Kernel(const float* __restrict__ err,
                                                   float* __restrict__ wsf,
                                                   unsigned* __restrict__ wsu){
  __shared__ unsigned h2[4096];
  __shared__ float s2[4096];
  __shared__ float ls[4];
  int tid = threadIdx.x;
  for (int i=tid;i<4096;i+=256){ h2[i]=0u; s2[i]=0.f; }
  __syncthreads();
  float lo = funkey(wsu[WS_MINKEY]);
  float hi = funkey(wsu[WS_MAXKEY]);
  float invw = 4096.f / fmaxf(hi-lo, 1e-30f);
  int bstar = (int)wsu[WS_BSTAR];
  float lo2 = wsf[WS_LO2];
  float w2  = wsf[WS_W2];
  float invw2 = 1.f / w2;
  float mySum = 0.f;
  int base = blockIdx.x*2048 + tid;
  for (int j=0;j<8;j++){
    float v = err[base + j*256];
    int idx = (int)fminf(fmaxf((v-lo)*invw, 0.f), 4095.f);
    if (idx > bstar){
      mySum += v;
    } else if (idx == bstar){
      int i2 = (int)fminf(fmaxf((v-lo2)*invw2, 0.f), 4095.f);
      atomicAdd(&h2[i2], 1u);
      atomicAdd(&s2[i2], v);
    }
  }
  for (int off=1; off<64; off<<=1) mySum += __shfl_xor(mySum, off);
  if ((tid&63)==0) ls[tid>>6] = mySum;
  __syncthreads();
  if (tid==0) atomicAdd(&wsf[WS_SUMAB], ls[0]+ls[1]+ls[2]+ls[3]);
  for (int i=tid;i<4096;i+=256){
    unsigned c = h2[i]; if (c) atomicAdd(&wsu[WS_H2C+i], c);
    float sv = s2[i];   if (sv != 0.f) atomicAdd(&wsf[WS_H2S+i], sv);
  }
}

__global__ __launch_bounds__(256) void scan2Kernel(float* __restrict__ wsf,
                                                   unsigned* __restrict__ wsu,
                                                   float* __restrict__ out){
  __shared__ unsigned cnt[4096];
  __shared__ float sm[4096];
  __shared__ unsigned sC[256];
  __shared__ float sS[256];
  int tid = threadIdx.x;
  for (int i=tid;i<4096;i+=256){ cnt[i]=wsu[WS_H2C+i]; sm[i]=wsf[WS_H2S+i]; }
  __syncthreads();
  unsigned pc=0; float ps=0.f;
  for (int j=0;j<16;j++){ pc+=cnt[tid*16+j]; ps+=sm[tid*16+j]; }
  sC[tid]=pc; sS[tid]=ps; __syncthreads();
  for (int off=1; off<256; off<<=1){
    unsigned vc = (tid+off<256)? sC[tid+off] : 0u;
    float vs    = (tid+off<256)? sS[tid+off] : 0.f;
    __syncthreads();
    sC[tid] += vc; sS[tid] += vs;
    __syncthreads();
  }
  unsigned k2 = wsu[WS_K2];
  float lo2 = wsf[WS_LO2], w2 = wsf[WS_W2];
  unsigned cum = (tid<255)? sC[tid+1] : 0u;
  float cums   = (tid<255)? sS[tid+1] : 0.f;
  for (int j=15;j>=0;j--){
    int bin = tid*16+j;
    unsigned cn = cum + cnt[bin];
    float sn = cums + sm[bin];
    if (cum < k2 && cn >= k2){
      float val = lo2 + ((float)bin + 0.5f)*w2;
      float total = wsf[WS_SUMAB] + cums + (float)(k2 - cum)*val;
      out[0] = total / (float)KTOP;
    }
    cum = cn; cums = sn;
  }
}

extern "C" void kernel_launch(void* const* d_in, const int* in_sizes, int n_in,
                              void* d_out, int out_size, void* d_ws, size_t ws_size,
                              hipStream_t stream){
  const float* rec = (const float*)d_in[0];
  const float* tgt = (const float*)d_in[1];
  const float* lw  = (const float*)d_in[2];
  float* out = (float*)d_out;
  float* wsf = (float*)d_ws;
  unsigned* wsu = (unsigned*)d_ws;

  hipLaunchKernelGGL(initWs, dim3((WS_TOTAL+255)/256), dim3(256), 0, stream, wsu);
  hipLaunchKernelGGL(bnSumKernel, dim3(1024), dim3(512), 0, stream, rec, tgt, wsf);
  hipLaunchKernelGGL(finalizeKernel, dim3(1), dim3(256), 0, stream, lw, wsf);
  hipLaunchKernelGGL(mainKernel, dim3(NPIX/64), dim3(256), 0, stream, rec, tgt, wsf, wsu, out+1);
  hipLaunchKernelGGL(hist1Kernel, dim3(128), dim3(256), 0, stream, out+1, wsu);
  hipLaunchKernelGGL(scan1Kernel, dim3(1), dim3(256), 0, stream, wsf, wsu);
  hipLaunchKernelGGL(hist2Kernel, dim3(128), dim3(256), 0, stream, out+1, wsf, wsu);
  hipLaunchKernelGGL(scan2Kernel, dim3(1), dim3(256), 0, stream, wsf, wsu, out);
}